// Round 18
// baseline (74.088 us; speedup 1.0000x reference)
//
#include <hip/hip_runtime.h>
#include <hip/hip_bf16.h>

// Problem constants
#define BHALF 4096      // B = 8192/2
#define DDIM 128        // feature dim per matrix
#define KCAT 384        // 3*DDIM, packed row width
#define TEMP_INV 10.0f  // 1/TEMP
#define EXP2K 14.426950408889634f  // 10 * log2(e): exp(v*10) = exp2(v*EXP2K)
#define PSTRIDE (64 * 4096)  // one partial-sum array: [slot 64][4096]

typedef __attribute__((ext_vector_type(8))) short short8;   // 8 bf16
typedef __attribute__((ext_vector_type(4))) float f32x4;    // 16x16 MFMA acc

// Async global->LDS, 16B per lane. LDS dest is wave-uniform base (HW adds
// lane*16). Global source is per-lane.
__device__ __forceinline__ void gload16(const ushort* g, ushort* l) {
  __builtin_amdgcn_global_load_lds(
      (const __attribute__((address_space(1))) unsigned int*)g,
      (__attribute__((address_space(3))) unsigned int*)l, 16, 0, 0);
}

// ---------------------------------------------------------------------------
// Fused normalize + diag: one wave per (matrix, row-pair i). [R13 verbatim]
__global__ __launch_bounds__(256) void norm_diag_kernel(
    const float* __restrict__ x, const float* __restrict__ y,
    const float* __restrict__ z, ushort* __restrict__ nrm1,
    ushort* __restrict__ nrm2, float* __restrict__ dxyz) {
  int wave = threadIdx.x >> 6;
  int lane = threadIdx.x & 63;
  int gi = blockIdx.x * 4 + wave;  // 0 .. 3*4096-1
  int mat = gi >> 12;
  int i = gi & 4095;
  const float* src = (mat == 0 ? x : (mat == 1 ? y : z));
  float2 a = *(const float2*)(src + (size_t)i * DDIM + lane * 2);
  float2 b = *(const float2*)(src + (size_t)(i + BHALF) * DDIM + lane * 2);
  float s1 = a.x * a.x + a.y * a.y;
  float s2 = b.x * b.x + b.y * b.y;
  float d = a.x * b.x + a.y * b.y;
#pragma unroll
  for (int m = 1; m < 64; m <<= 1) {
    s1 += __shfl_xor(s1, m, 64);
    s2 += __shfl_xor(s2, m, 64);
    d += __shfl_xor(d, m, 64);
  }
  float r1 = 1.0f / fmaxf(sqrtf(s1), 1e-12f);
  float r2 = 1.0f / fmaxf(sqrtf(s2), 1e-12f);
  ushort* d1 = nrm1 + (size_t)i * KCAT + mat * DDIM + lane * 2;
  ushort* d2 = nrm2 + (size_t)i * KCAT + mat * DDIM + lane * 2;
  __hip_bfloat162 o1, o2;
  o1.x = __float2bfloat16(a.x * r1);
  o1.y = __float2bfloat16(a.y * r1);
  o2.x = __float2bfloat16(b.x * r2);
  o2.y = __float2bfloat16(b.y * r2);
  *(__hip_bfloat162*)d1 = o1;
  *(__hip_bfloat162*)d2 = o2;
  if (lane == 0) dxyz[mat * BHALF + i] = d * r1 * r2;
}

// ---------------------------------------------------------------------------
// Flush helpers — plain STORES to per-(block,wave) partial slots (no
// atomics; each slot written exactly once). [R13 verbatim]
// 16x16 C/D layout (verified R1/R2): col = lane&15, row = (lane>>4)*4 + r.

__device__ __forceinline__ void flush_cheap(f32x4 (&acc)[4][4],
                                            float* __restrict__ dst, int base,
                                            int lane) {
#pragma unroll
  for (int m = 0; m < 4; ++m) {
    float s = 0.0f;
#pragma unroll
    for (int n = 0; n < 4; ++n)
#pragma unroll
      for (int r = 0; r < 4; ++r) s += exp2f(acc[m][n][r] * EXP2K);
    s += __shfl_xor(s, 16, 64);
    s += __shfl_xor(s, 32, 64);
    if (lane < 16) dst[base + m * 16 + lane] = s;
  }
}

__device__ __forceinline__ void flush_full(f32x4 (&acc)[4][4],
                                           float* __restrict__ rs,
                                           float* __restrict__ cs, int rbase,
                                           int cbase, int lane) {
#pragma unroll
  for (int m = 0; m < 4; ++m)
#pragma unroll
    for (int n = 0; n < 4; ++n)
#pragma unroll
      for (int r = 0; r < 4; ++r)
        acc[m][n][r] = exp2f(acc[m][n][r] * EXP2K);

  // row sums: reduce over cols (n + xor over lane&15)
#pragma unroll
  for (int m = 0; m < 4; ++m) {
    float rsum[4];
#pragma unroll
    for (int r = 0; r < 4; ++r)
      rsum[r] = acc[m][0][r] + acc[m][1][r] + acc[m][2][r] + acc[m][3][r];
#pragma unroll
    for (int r = 0; r < 4; ++r) {
      rsum[r] += __shfl_xor(rsum[r], 1, 64);
      rsum[r] += __shfl_xor(rsum[r], 2, 64);
      rsum[r] += __shfl_xor(rsum[r], 4, 64);
      rsum[r] += __shfl_xor(rsum[r], 8, 64);
    }
    if ((lane & 15) == 0) {
      int rb = rbase + m * 16 + (lane >> 4) * 4;
#pragma unroll
      for (int r = 0; r < 4; ++r) rs[rb + r] = rsum[r];
    }
  }

  // col sums: reduce over rows (m, r, xor16, xor32)
#pragma unroll
  for (int n = 0; n < 4; ++n) {
    float csum = 0.0f;
#pragma unroll
    for (int m = 0; m < 4; ++m)
#pragma unroll
      for (int r = 0; r < 4; ++r) csum += acc[m][n][r];
    csum += __shfl_xor(csum, 16, 64);
    csum += __shfl_xor(csum, 32, 64);
    if (lane < 16) cs[cbase + n * 16 + lane] = csum;
  }
}

// ---------------------------------------------------------------------------
// Gram kernel: R13/R17-verbatim body; ONLY change is XCD-aware tile
// swizzle (T1). Diagnosis (R17): staged traffic 393 MB / 59 us = 6.7 TB/s
// = L3 ceiling, because the 6.3 MB working set exceeds each XCD's 4 MB L2
// and round-robin dispatch makes every XCD touch everything. Fix: within
// each gram phase (1024 tiles), remap flattened id so XCD x (= id%8, HW
// round-robin; +1024z preserves mod 8) executes exactly bj in [4x,4x+4),
// bi in [0,32): per-XCD WS = 3.5 MB (g3) / ~2.3 MB (g0-2) -> L2-resident.
// parts layout: 7 arrays of [slot 64][4096]:
//   a0 rs0(slot bj*2+wc) a1 cs0(bi*2+wr) a2 rs1 a3 cs1 a4 rs2 a5 cs2 a6 rs3
__global__ __launch_bounds__(256) void gram_slab_kernel(
    const ushort* __restrict__ nrm1, const ushort* __restrict__ nrm2,
    float* __restrict__ parts) {
  __shared__ ushort As[4][128][32];  // 32 KB, kslice-major (64B rows)
  __shared__ ushort Bs[4][128][32];  // 32 KB

  int tid = threadIdx.x;
  int lane = tid & 63;
  int wave = tid >> 6;  // 0..3
  int wr = wave >> 1;   // 0..1: rows wr*64
  int wc = wave & 1;    // 0..1: cols wc*64
  int g = (blockIdx.z == 0) ? 3 : (int)blockIdx.z - 1;  // heavy g3 first
  // XCD-aware swizzle: fid%8 = XCD; give XCD x a contiguous bj slice.
  int fid = (int)blockIdx.x + 32 * (int)blockIdx.y;  // 0..1023 in phase
  int swz = (fid & 7) * 128 + (fid >> 3);
  int bi = swz & 31;
  int bj = swz >> 5;
  int rowbase = bi * 128;
  int colbase = bj * 128;

  const ushort* Ab;
  const ushort* Bb;
  int nslab;
  float* rs;  // row-type slot base (indexed by bj*2+wc)
  float* cs;  // col-type slot base (indexed by bi*2+wr)
  int rslot = (bj * 2 + wc) * 4096;
  int cslot = (bi * 2 + wr) * 4096;
  if (g == 3) {
    Ab = nrm1;       Bb = nrm2;       nslab = 3;
    rs = parts + 6 * PSTRIDE + rslot; cs = nullptr;
  } else if (g == 0) {
    Ab = nrm1;       Bb = nrm1 + 128; nslab = 1;
    rs = parts + 0 * PSTRIDE + rslot; cs = parts + 1 * PSTRIDE + cslot;
  } else if (g == 1) {
    Ab = nrm1;       Bb = nrm1 + 256; nslab = 1;
    rs = parts + 2 * PSTRIDE + rslot; cs = parts + 3 * PSTRIDE + cslot;
  } else {
    Ab = nrm1 + 128; Bb = nrm1 + 256; nslab = 1;
    rs = parts + 4 * PSTRIDE + rslot; cs = parts + 5 * PSTRIDE + cslot;
  }

  // Staging: lane l -> LDS row +(l>>2) (16 rows/load), chunk (l&3); source
  // chunk pre-swizzled by ((l>>3)&3) = ((row mod 16)>>1)&3 (R2-verified).
  int srow = lane >> 2;
  int schunk = ((lane & 3) ^ ((lane >> 3) & 3)) << 3;
  const ushort* gA =
      Ab + (size_t)(rowbase + wave * 32 + srow) * KCAT + schunk;
  const ushort* gB =
      Bb + (size_t)(colbase + wave * 32 + srow) * KCAT + schunk;

  // Fragment reads: row = grp*16 + rsel, logical chunk = lane>>4,
  // physical slot = chunk ^ ((rsel>>1)&3).
  int rsel = lane & 15;
  int slot8 = (((lane >> 4) ^ ((rsel >> 1) & 3)) << 3);

  f32x4 acc[4][4] = {};

  for (int slab = 0; slab < nslab; ++slab) {
    if (slab) {
      __builtin_amdgcn_s_barrier();       // prev slab reads done everywhere
      __builtin_amdgcn_sched_barrier(0);  // keep stage below the barrier
    }
    int k0 = slab * 128;
#pragma unroll
    for (int s = 0; s < 4; ++s) {
#pragma unroll
      for (int rg = 0; rg < 2; ++rg) {
        gload16(gA + k0 + s * 32 + (size_t)rg * 16 * KCAT,
                &As[s][wave * 32 + rg * 16][0]);
        gload16(gB + k0 + s * 32 + (size_t)rg * 16 * KCAT,
                &Bs[s][wave * 32 + rg * 16][0]);
      }
    }
    asm volatile("s_waitcnt vmcnt(0)" ::: "memory");
    __builtin_amdgcn_s_barrier();
    __builtin_amdgcn_sched_barrier(0);  // no LDS-read hoisting above barrier

    if (g == 3) {
#pragma unroll
      for (int kk = 0; kk < 4; ++kk) {
        short8 af[4], bf[4];
#pragma unroll
        for (int m = 0; m < 4; ++m)
          af[m] = *(const short8*)&As[kk][wr * 64 + m * 16 + rsel][slot8];
#pragma unroll
        for (int n = 0; n < 4; ++n)
          bf[n] = *(const short8*)&Bs[kk][wc * 64 + n * 16 + rsel][slot8];
#pragma unroll
        for (int m = 0; m < 4; ++m)
#pragma unroll
          for (int n = 0; n < 4; ++n)
            acc[m][n] = __builtin_amdgcn_mfma_f32_16x16x32_bf16(
                bf[n], af[m], acc[m][n], 0, 0, 0);
      }
    } else {
#pragma unroll
      for (int kk = 0; kk < 4; ++kk) {
        short8 af[4], bf[4];
#pragma unroll
        for (int m = 0; m < 4; ++m)
          af[m] = *(const short8*)&As[kk][wr * 64 + m * 16 + rsel][slot8];
#pragma unroll
        for (int n = 0; n < 4; ++n)
          bf[n] = *(const short8*)&Bs[kk][wc * 64 + n * 16 + rsel][slot8];
#pragma unroll
        for (int m = 0; m < 4; ++m)
#pragma unroll
          for (int n = 0; n < 4; ++n)
            acc[m][n] = __builtin_amdgcn_mfma_f32_16x16x32_bf16(
                af[m], bf[n], acc[m][n], 0, 0, 0);
      }
    }
  }

  if (g == 3)
    flush_cheap(acc, rs, rowbase + wr * 64, lane);
  else
    flush_full(acc, rs, cs, rowbase + wr * 64, colbase + wc * 64, lane);
}

// ---------------------------------------------------------------------------
// Stage 1: fold the 64 partial slots of each of the 7 arrays. [R17 verbatim]
__global__ __launch_bounds__(256) void reduce_parts_kernel(
    const float* __restrict__ parts, float* __restrict__ sums7) {
  int f = blockIdx.x * 256 + threadIdx.x;  // 0 .. 7*4096-1
  int a = f >> 12;
  int i = f & 4095;
  const float* p = parts + (size_t)a * PSTRIDE + i;
  float s = 0.0f;
#pragma unroll 8
  for (int slot = 0; slot < 64; ++slot) s += p[slot * 4096];
  sums7[f] = s;
}

// ---------------------------------------------------------------------------
// Stage 2: final loss from folded sums (163 KB read). [R17 verbatim]
__global__ __launch_bounds__(256) void loss_kernel(
    const float* __restrict__ s7, const float* __restrict__ dxyz,
    float* __restrict__ out) {
  int i = blockIdx.x * 256 + threadIdx.x;  // 0..4095
  float rs0 = s7[i];
  float cs0 = s7[4096 + i];
  float rs1 = s7[2 * 4096 + i];
  float cs1 = s7[3 * 4096 + i];
  float rs2 = s7[4 * 4096 + i];
  float cs2 = s7[5 * 4096 + i];
  float rs3 = s7[6 * 4096 + i];
  float dxv = dxyz[i];
  float dyv = dxyz[4096 + i];
  float dzv = dxyz[2 * 4096 + i];
  float lx = logf(rs0 + rs1) - TEMP_INV * dxv;
  float ly = logf(cs0 + rs2) - TEMP_INV * dyv;
  float lz = logf(cs1 + cs2) - TEMP_INV * dzv;
  float lv = logf(rs3) - TEMP_INV * (dxv + dyv + dzv);
  float acc = (lx + ly + lz + lv) * (1.0f / 4096.0f);
#pragma unroll
  for (int m = 1; m < 64; m <<= 1) acc += __shfl_xor(acc, m, 64);
  __shared__ float red[4];
  if ((threadIdx.x & 63) == 0) red[threadIdx.x >> 6] = acc;
  __syncthreads();
  if (threadIdx.x == 0)
    atomicAdd(out, red[0] + red[1] + red[2] + red[3]);
}

// ---------------------------------------------------------------------------
extern "C" void kernel_launch(void* const* d_in, const int* in_sizes, int n_in,
                              void* d_out, int out_size, void* d_ws,
                              size_t ws_size, hipStream_t stream) {
  const float* x = (const float*)d_in[0];
  const float* y = (const float*)d_in[1];
  const float* z = (const float*)d_in[2];
  char* ws = (char*)d_ws;
  ushort* nrm1 = (ushort*)ws;                       // 4096*384 bf16
  ushort* nrm2 = nrm1 + (size_t)BHALF * KCAT;       // 4096*384 bf16
  float* parts = (float*)(ws + 2 * (size_t)BHALF * KCAT * sizeof(ushort));
  float* dxyz = parts + 7 * PSTRIDE;                // 3*4096 fp32
  float* sums7 = dxyz + 3 * 4096;                   // 7*4096 fp32

  hipMemsetAsync(d_out, 0, sizeof(float), stream);
  norm_diag_kernel<<<3 * BHALF / 4, 256, 0, stream>>>(x, y, z, nrm1, nrm2,
                                                      dxyz);
  gram_slab_kernel<<<dim3(32, 32, 4), 256, 0, stream>>>(nrm1, nrm2, parts);
  reduce_parts_kernel<<<112, 256, 0, stream>>>(parts, sums7);
  loss_kernel<<<16, 256, 0, stream>>>(sums7, dxyz, (float*)d_out);
}